// Round 1
// 1055.166 us; speedup vs baseline: 1.1797x; 1.1797x over previous
//
#include <hip/hip_runtime.h>
#include <cstddef>

#define SEQ   2048
#define BATCH 2
#define EMB   768
#define NHEAD 12
#define HD    64
#define NHT   (BATCH * NHEAD)   // 24 head-batches
#define MROWS (SEQ * BATCH)     // 4096 token rows
#define N1    (MROWS * EMB)     // 3145728 elements (X / Y matrices)
#define N2    (EMB * EMB)       // 589824 elements  (weight matrices)

typedef __attribute__((ext_vector_type(8))) short short8v;            // 8 bf16 (4 VGPR) MFMA frag
typedef __attribute__((ext_vector_type(8))) unsigned short ushort8v;
typedef __attribute__((ext_vector_type(4))) float float4v;            // MFMA C/D frag

// ---------- bf16 helpers (RNE; inputs finite) ----------
__device__ __forceinline__ unsigned short f2bf(float f) {
  unsigned int u = __float_as_uint(f);
  u += 0x7FFFu + ((u >> 16) & 1u);
  return (unsigned short)(u >> 16);
}
__device__ __forceinline__ float bf2f(unsigned short h) {
  return __uint_as_float((unsigned int)h << 16);
}

// ---------- split-cast: fp32 -> (hi, lo) bf16 planes ----------
// hi = bf16(x), lo = bf16(x - hi): x == hi+lo to ~2^-17 relative.
__device__ __forceinline__ void split8(const float* __restrict__ x,
                                       unsigned short* __restrict__ h,
                                       unsigned short* __restrict__ l,
                                       size_t i0)
{
  const float4 a = *(const float4*)(x + i0);
  const float4 b = *(const float4*)(x + i0 + 4);
  const float xv[8] = {a.x, a.y, a.z, a.w, b.x, b.y, b.z, b.w};
  ushort8v hv, lv;
#pragma unroll
  for (int j = 0; j < 8; ++j) {
    const unsigned short hh = f2bf(xv[j]);
    hv[j] = hh;
    lv[j] = f2bf(xv[j] - bf2f(hh));   // exact residual in fp32, then rounded
  }
  *(ushort8v*)(h + i0) = hv;   // 16B stores, i0 multiple of 8 elems
  *(ushort8v*)(l + i0) = lv;
}

__global__ __launch_bounds__(256) void cast_split_x_kernel(
    const float* __restrict__ x0, const float* __restrict__ x1,
    const float* __restrict__ x2, unsigned short* __restrict__ base)
{
  const int z = blockIdx.z;
  const float* x = (z == 0) ? x0 : (z == 1) ? x1 : x2;
  unsigned short* h = base + (size_t)z * (2 * (size_t)N1);
  unsigned short* l = h + N1;
  const size_t i0 = ((size_t)blockIdx.x * 256 + threadIdx.x) * 8;
  split8(x, h, l, i0);
}

__global__ __launch_bounds__(256) void cast_split_w_kernel(
    const float* __restrict__ w0, const float* __restrict__ w1,
    const float* __restrict__ w2, const float* __restrict__ w3,
    unsigned short* __restrict__ wbase, unsigned short* __restrict__ wobase)
{
  const int z = blockIdx.z;
  const float* w = (z == 0) ? w0 : (z == 1) ? w1 : (z == 2) ? w2 : w3;
  unsigned short* h = (z < 3) ? (wbase + (size_t)z * (2 * (size_t)N2)) : wobase;
  unsigned short* l = h + N2;
  const size_t i0 = ((size_t)blockIdx.x * 256 + threadIdx.x) * 8;
  split8(w, h, l, i0);
}

__global__ __launch_bounds__(256) void cast_split_one_kernel(
    const float* __restrict__ x, unsigned short* __restrict__ h,
    unsigned short* __restrict__ l)
{
  const size_t i0 = ((size_t)blockIdx.x * 256 + threadIdx.x) * 8;
  split8(x, h, l, i0);
}

// ---------- async global->LDS (16B/lane, wave-uniform LDS base) ----------
__device__ __forceinline__ void async16(const void* g, void* l) {
  __builtin_amdgcn_global_load_lds(
      (const __attribute__((address_space(1))) void*)g,
      (__attribute__((address_space(3))) void*)l, 16, 0, 0);
}

// ===================== bf16x3 split MFMA GEMM =====================
// Y[m][n] = sum_k X[m][k]*W[n][k] + bias[n], computed as
// Xhi*Whi + Xhi*Wlo + Xlo*Whi in fp32 MFMA accumulators.
// 128x128 tile, 4 waves (2x2), 64x64 per wave, BK=32, mfma_f32_16x16x32_bf16.
__device__ __forceinline__ void gemm_mfma_body(
    const unsigned short* __restrict__ XH, const unsigned short* __restrict__ XL,
    const unsigned short* __restrict__ WH, const unsigned short* __restrict__ WL,
    const float* __restrict__ bias, float* __restrict__ out, const int headsplit)
{
  __shared__ __align__(16) unsigned short AsH[128][32];
  __shared__ __align__(16) unsigned short AsL[128][32];
  __shared__ __align__(16) unsigned short BsH[128][32];
  __shared__ __align__(16) unsigned short BsL[128][32];

  const int tid  = threadIdx.x;
  const int wid  = tid >> 6;          // wave 0..3
  const int lane = tid & 63;
  const int m0 = blockIdx.x * 128;
  const int n0 = blockIdx.y * 128;
  const int wr = (wid >> 1) * 64;     // wave M-base within tile
  const int wc = (wid & 1) * 64;      // wave N-base within tile

  // staging: each wave fills chunks {2w, 2w+1} of each 8KB plane.
  // chunk c = 16 rows of 64B; lane covers row 16c+(lane>>2), col (lane&3)*8.
  const int c0   = wid * 2;
  const int srow = lane >> 2;
  const int scol = (lane & 3) * 8;

  // fragment addressing (16x16x32 bf16):
  // A: row = lane&15, k = (lane>>4)*8 + e ; B: col = lane&15, same k.
  const int fr = lane & 15;
  const int fg = (lane >> 4) * 8;

  float4v acc[4][4] = {};   // 64 fp32 accum regs

  for (int k0 = 0; k0 < EMB; k0 += 32) {
#pragma unroll
    for (int cc = 0; cc < 2; ++cc) {
      const int c  = c0 + cc;
      const size_t ga = (size_t)(m0 + c * 16 + srow) * EMB + (k0 + scol);
      const size_t gb = (size_t)(n0 + c * 16 + srow) * EMB + (k0 + scol);
      async16(XH + ga, &AsH[c * 16][0]);
      async16(XL + ga, &AsL[c * 16][0]);
      async16(WH + gb, &BsH[c * 16][0]);
      async16(WL + gb, &BsL[c * 16][0]);
    }
    __syncthreads();   // drains vmcnt: LDS tiles complete

    short8v aH[4], aL[4], bH[4], bL[4];
#pragma unroll
    for (int i = 0; i < 4; ++i) {
      aH[i] = *(const short8v*)&AsH[wr + i * 16 + fr][fg];
      aL[i] = *(const short8v*)&AsL[wr + i * 16 + fr][fg];
      bH[i] = *(const short8v*)&BsH[wc + i * 16 + fr][fg];
      bL[i] = *(const short8v*)&BsL[wc + i * 16 + fr][fg];
    }
#pragma unroll
    for (int i = 0; i < 4; ++i)
#pragma unroll
      for (int j = 0; j < 4; ++j) {
        acc[i][j] = __builtin_amdgcn_mfma_f32_16x16x32_bf16(aH[i], bH[j], acc[i][j], 0, 0, 0);
        acc[i][j] = __builtin_amdgcn_mfma_f32_16x16x32_bf16(aH[i], bL[j], acc[i][j], 0, 0, 0);
        acc[i][j] = __builtin_amdgcn_mfma_f32_16x16x32_bf16(aL[i], bH[j], acc[i][j], 0, 0, 0);
      }
    __syncthreads();   // all frag reads done before next stage overwrites
  }

  // epilogue: C/D layout col = lane&15, row = (lane>>4)*4 + reg  [m89-verified]
  const int rbase = (lane >> 4) * 4;
#pragma unroll
  for (int j = 0; j < 4; ++j) {
    const int col = n0 + wc + j * 16 + fr;
    const float bv = bias[col];
#pragma unroll
    for (int i = 0; i < 4; ++i) {
#pragma unroll
      for (int r = 0; r < 4; ++r) {
        const int m = m0 + wr + i * 16 + rbase + r;
        const float val = acc[i][j][r] + bv;
        if (headsplit) {
          const int s = m >> 1, b = m & 1;          // m = s*BATCH + b
          const int h = col >> 6, d = col & 63;
          out[((size_t)(b * NHEAD + h) * SEQ + s) * HD + d] = val;
        } else {
          out[(size_t)m * EMB + col] = val;
        }
      }
    }
  }
}

__global__ __launch_bounds__(256) void qkv_gemm_mfma_kernel(
    const unsigned short* __restrict__ sc,
    const float* __restrict__ bq, const float* __restrict__ bk,
    const float* __restrict__ bv, float* __restrict__ outbase)
{
  const int z = blockIdx.z;   // 0=Q,1=K,2=V (uniform)
  const unsigned short* XH = sc + (size_t)z * (2 * (size_t)N1);
  const unsigned short* XL = XH + N1;
  const unsigned short* WH = sc + 6 * (size_t)N1 + (size_t)z * (2 * (size_t)N2);
  const unsigned short* WL = WH + N2;
  const float* bias = (z == 0) ? bq : (z == 1) ? bk : bv;
  gemm_mfma_body(XH, XL, WH, WL, bias, outbase + (size_t)z * N1, 1);
}

__global__ __launch_bounds__(256) void oproj_mfma_kernel(
    const unsigned short* __restrict__ XH, const unsigned short* __restrict__ XL,
    const unsigned short* __restrict__ WH, const unsigned short* __restrict__ WL,
    const float* __restrict__ bias, float* __restrict__ out)
{
  gemm_mfma_body(XH, XL, WH, WL, bias, out, 0);
}

// ===================== fused attention (unchanged) =====================
__global__ __launch_bounds__(256) void attn_kernel(
    const float* __restrict__ Qh, const float* __restrict__ Kh,
    const float* __restrict__ Vh, float* __restrict__ attnw,
    float* __restrict__ ctxbuf, float* __restrict__ invl)
{
  __shared__ float Qs[64][64];   // [d][q]  (transposed)
  __shared__ float Ks[64][64];   // [d][k]  (transposed)
  __shared__ float Vs[64][64];   // [k][d]  (natural)

  const int tid = threadIdx.x;
  const int n  = blockIdx.y;          // 0..23
  const int q0 = blockIdx.x * 64;     // query tile base

  const float* Qn = Qh + ((size_t)n * SEQ + q0) * HD;
  const float* Kn = Kh + (size_t)n * SEQ * HD;
  const float* Vn = Vh + (size_t)n * SEQ * HD;

  const int lr = tid >> 2;            // 0..63 row
  const int lc = (tid & 3) * 16;      // 0,16,32,48 col base

  {  // stage Q tile transposed (once)
    const float* qp = Qn + lr * HD + lc;
    const float4 v0 = *(const float4*)qp;
    const float4 v1 = *(const float4*)(qp + 4);
    const float4 v2 = *(const float4*)(qp + 8);
    const float4 v3 = *(const float4*)(qp + 12);
    Qs[lc + 0][lr] = v0.x; Qs[lc + 1][lr] = v0.y; Qs[lc + 2][lr] = v0.z; Qs[lc + 3][lr] = v0.w;
    Qs[lc + 4][lr] = v1.x; Qs[lc + 5][lr] = v1.y; Qs[lc + 6][lr] = v1.z; Qs[lc + 7][lr] = v1.w;
    Qs[lc + 8][lr] = v2.x; Qs[lc + 9][lr] = v2.y; Qs[lc +10][lr] = v2.z; Qs[lc +11][lr] = v2.w;
    Qs[lc +12][lr] = v3.x; Qs[lc +13][lr] = v3.y; Qs[lc +14][lr] = v3.z; Qs[lc +15][lr] = v3.w;
  }

  const int tq = tid >> 4;   // 0..15: q-group (phase 1 & 2)
  const int tk = tid & 15;   // 0..15: k-group (phase 1) / d-group (phase 2)

  float ctx[4][4];
  float pr[4];
#pragma unroll
  for (int i = 0; i < 4; ++i) {
    pr[i] = 0.0f;
#pragma unroll
    for (int j = 0; j < 4; ++j) ctx[i][j] = 0.0f;
  }

  for (int kt = 0; kt < SEQ / 64; ++kt) {
    const int k0 = kt * 64;
    // ---- stage K (transposed) and V (natural) ----
    const float* kp = Kn + (size_t)(k0 + lr) * HD + lc;
    const float4 ka = *(const float4*)kp;
    const float4 kb = *(const float4*)(kp + 4);
    const float4 kc = *(const float4*)(kp + 8);
    const float4 kd = *(const float4*)(kp + 12);
    const float* vp = Vn + (size_t)(k0 + lr) * HD + lc;
    const float4 va = *(const float4*)vp;
    const float4 vb = *(const float4*)(vp + 4);
    const float4 vc = *(const float4*)(vp + 8);
    const float4 vd = *(const float4*)(vp + 12);

    __syncthreads();   // prev tile's LDS use done
    Ks[lc + 0][lr] = ka.x; Ks[lc + 1][lr] = ka.y; Ks[lc + 2][lr] = ka.z; Ks[lc + 3][lr] = ka.w;
    Ks[lc + 4][lr] = kb.x; Ks[lc + 5][lr] = kb.y; Ks[lc + 6][lr] = kb.z; Ks[lc + 7][lr] = kb.w;
    Ks[lc + 8][lr] = kc.x; Ks[lc + 9][lr] = kc.y; Ks[lc +10][lr] = kc.z; Ks[lc +11][lr] = kc.w;
    Ks[lc +12][lr] = kd.x; Ks[lc +13][lr] = kd.y; Ks[lc +14][lr] = kd.z; Ks[lc +15][lr] = kd.w;
    *(float4*)&Vs[lr][lc + 0]  = va;
    *(float4*)&Vs[lr][lc + 4]  = vb;
    *(float4*)&Vs[lr][lc + 8]  = vc;
    *(float4*)&Vs[lr][lc + 12] = vd;
    __syncthreads();

    // ---- phase 1: scores 64q x 64k ----
    float s[4][4];
#pragma unroll
    for (int i = 0; i < 4; ++i)
#pragma unroll
      for (int j = 0; j < 4; ++j) s[i][j] = 0.0f;

#pragma unroll 8
    for (int d = 0; d < 64; ++d) {
      const float4 qa = *(const float4*)&Qs[d][tq * 4];
      const float4 kk4 = *(const float4*)&Ks[d][tk * 4];
      const float qv[4] = {qa.x, qa.y, qa.z, qa.w};
      const float kv[4] = {kk4.x, kk4.y, kk4.z, kk4.w};
#pragma unroll
      for (int i = 0; i < 4; ++i)
#pragma unroll
        for (int j = 0; j < 4; ++j)
          s[i][j] = fmaf(qv[i], kv[j], s[i][j]);
    }

    const size_t abase = ((size_t)n * SEQ + q0 + tq * 4) * SEQ + k0 + tk * 4;
#pragma unroll
    for (int qq = 0; qq < 4; ++qq) {
      const float e0 = __expf(s[qq][0] * 0.125f);
      const float e1 = __expf(s[qq][1] * 0.125f);
      const float e2 = __expf(s[qq][2] * 0.125f);
      const float e3 = __expf(s[qq][3] * 0.125f);
      pr[qq] += (e0 + e1) + (e2 + e3);
      float4 ev; ev.x = e0; ev.y = e1; ev.z = e2; ev.w = e3;
      *(float4*)(attnw + abase + (size_t)qq * SEQ) = ev;
    }
    __syncthreads();   // drains vmcnt: e stores visible to whole block

    // ---- phase 2: ctx += e * V ----
    const float* erd = attnw + ((size_t)n * SEQ + q0 + tq * 4) * SEQ + k0;
#pragma unroll 4
    for (int kk = 0; kk < 64; kk += 4) {
      const float4 t0 = *(const float4*)(erd + kk);
      const float4 t1 = *(const float4*)(erd + SEQ + kk);
      const float4 t2 = *(const float4*)(erd + 2 * SEQ + kk);
      const float4 t3 = *(const float4*)(erd + 3 * SEQ + kk);
      const float ea[4][4] = {{t0.x, t0.y, t0.z, t0.w},
                              {t1.x, t1.y, t1.z, t1.w},
                              {t2.x, t2.y, t2.z, t2.w},
                              {t3.x, t3.y, t3.z, t3.w}};
#pragma unroll
      for (int j = 0; j < 4; ++j) {
        const float4 vr = *(const float4*)&Vs[kk + j][tk * 4];
#pragma unroll
        for (int qq = 0; qq < 4; ++qq) {
          ctx[qq][0] = fmaf(ea[qq][j], vr.x, ctx[qq][0]);
          ctx[qq][1] = fmaf(ea[qq][j], vr.y, ctx[qq][1]);
          ctx[qq][2] = fmaf(ea[qq][j], vr.z, ctx[qq][2]);
          ctx[qq][3] = fmaf(ea[qq][j], vr.w, ctx[qq][3]);
        }
      }
    }
  }

  // ---- reduce row sums ----
  float* Pf = &Ks[0][0];
#pragma unroll
  for (int qq = 0; qq < 4; ++qq)
    Pf[(tq * 4 + qq) * 17 + tk] = pr[qq];
  __syncthreads();

  float* lsf = &Vs[0][0];
  if (tid < 64) {
    float sum = 0.0f;
#pragma unroll
    for (int c = 0; c < 16; ++c) sum += Pf[tid * 17 + c];
    const float inv = 1.0f / sum;
    lsf[tid] = inv;
    invl[(size_t)n * SEQ + q0 + tid] = inv;
  }
  __syncthreads();

  const int bb = n / NHEAD;
  const int hh = n % NHEAD;
#pragma unroll
  for (int qq = 0; qq < 4; ++qq) {
    const float il = lsf[tq * 4 + qq];
    const int r = (q0 + tq * 4 + qq) * BATCH + bb;
    float4 o;
    o.x = ctx[qq][0] * il; o.y = ctx[qq][1] * il;
    o.z = ctx[qq][2] * il; o.w = ctx[qq][3] * il;
    *(float4*)(ctxbuf + (size_t)r * EMB + hh * HD + tk * 4) = o;
  }
}

// ===================== normalize attn weights in place =====================
__global__ __launch_bounds__(256) void rescale_kernel(
    float4* __restrict__ attnw, const float* __restrict__ invl)
{
  const size_t n4 = (size_t)NHT * SEQ * SEQ / 4;
  size_t i = (size_t)blockIdx.x * 256 + threadIdx.x;
  const size_t stride = (size_t)gridDim.x * 256;
  for (; i < n4; i += stride) {
    const int row = (int)(i >> 9);
    const float il = invl[row];
    float4 v = attnw[i];
    v.x *= il; v.y *= il; v.z *= il; v.w *= il;
    attnw[i] = v;
  }
}

// ===================== launch =====================
extern "C" void kernel_launch(void* const* d_in, const int* in_sizes, int n_in,
                              void* d_out, int out_size, void* d_ws, size_t ws_size,
                              hipStream_t stream)
{
  (void)in_sizes; (void)n_in; (void)out_size; (void)ws_size;

  const float* q  = (const float*)d_in[0];
  const float* k  = (const float*)d_in[1];
  const float* v  = (const float*)d_in[2];
  const float* wq = (const float*)d_in[3];
  const float* wk = (const float*)d_in[4];
  const float* wv = (const float*)d_in[5];
  const float* bq = (const float*)d_in[6];
  const float* bk = (const float*)d_in[7];
  const float* bv = (const float*)d_in[8];
  const float* wo = (const float*)d_in[9];
  const float* bo = (const float*)d_in[10];

  float* out = (float*)d_out;
  float* attnw = out + (size_t)N1;               // output first, then weights

  float* ws   = (float*)d_ws;
  float* qh   = ws;                               // [24][2048][64] fp32
  float* ctxb = ws + 3 * (size_t)N1;              // [4096][768] fp32
  float* invl = ws + 4 * (size_t)N1;              // 24*2048 floats used

  // --- scratch placement (no new ws demand) ---
  // X/W bf16 hi-lo planes live in the attnw region (402 MB, fully
  // overwritten by attn_kernel later in the stream -> safe).
  unsigned short* sc  = (unsigned short*)attnw;          // 6*N1 + 6*N2 elems (~45 MB)
  unsigned short* wpl = sc + 6 * (size_t)N1;             // wq/wk/wv planes
  // W_O planes in the unused tail of the invl region (invl uses 49152 floats).
  unsigned short* wopl = (unsigned short*)(ws + 4 * (size_t)N1 + 65536);
  // ctx planes reuse the qh region (dead after attn_kernel). 2*N1 bf16 = exactly N1 floats.
  unsigned short* ctxH = (unsigned short*)qh;
  unsigned short* ctxL = ctxH + N1;

  cast_split_x_kernel<<<dim3(N1 / 2048, 1, 3), 256, 0, stream>>>(q, k, v, sc);
  cast_split_w_kernel<<<dim3(N2 / 2048, 1, 4), 256, 0, stream>>>(wq, wk, wv, wo, wpl, wopl);

  qkv_gemm_mfma_kernel<<<dim3(MROWS / 128, EMB / 128, 3), 256, 0, stream>>>(
      sc, bq, bk, bv, qh);

  attn_kernel<<<dim3(SEQ / 64, NHT), 256, 0, stream>>>(
      qh, ws + (size_t)N1, ws + 2 * (size_t)N1, attnw, ctxb, invl);

  rescale_kernel<<<dim3(8192), 256, 0, stream>>>((float4*)attnw, invl);

  cast_split_one_kernel<<<dim3(N1 / 2048), 256, 0, stream>>>(ctxb, ctxH, ctxL);

  oproj_mfma_kernel<<<dim3(MROWS / 128, EMB / 128), 256, 0, stream>>>(
      ctxH, ctxL, wopl, wopl + N2, bo, out);
}

// Round 2
// 680.508 us; speedup vs baseline: 1.8292x; 1.5506x over previous
//
#include <hip/hip_runtime.h>
#include <cstddef>

#define SEQ   2048
#define BATCH 2
#define EMB   768
#define NHEAD 12
#define HD    64
#define NHT   (BATCH * NHEAD)   // 24 head-batches
#define MROWS (SEQ * BATCH)     // 4096 token rows
#define N1    (MROWS * EMB)     // 3145728 elements (X / Y matrices)
#define N2    (EMB * EMB)       // 589824 elements  (weight matrices)
#define PLANE (SEQ * HD)        // 131072 elements per head-batch plane

typedef __attribute__((ext_vector_type(8))) short short8v;            // 8 bf16 MFMA frag
typedef __attribute__((ext_vector_type(8))) unsigned short ushort8v;
typedef __attribute__((ext_vector_type(4))) float float4v;            // MFMA C/D frag
typedef unsigned short u16;

// ---------- bf16 helpers (RNE; inputs finite) ----------
__device__ __forceinline__ u16 f2bf(float f) {
  unsigned int u = __float_as_uint(f);
  u += 0x7FFFu + ((u >> 16) & 1u);
  return (u16)(u >> 16);
}
__device__ __forceinline__ float bf2f(u16 h) {
  return __uint_as_float((unsigned int)h << 16);
}

// ---------- split-cast: fp32 -> (hi, lo) bf16 ----------
__device__ __forceinline__ void split8v(const float* __restrict__ p,
                                        ushort8v& hv, ushort8v& lv)
{
  const float4 a = *(const float4*)p;
  const float4 b = *(const float4*)(p + 4);
  const float xv[8] = {a.x, a.y, a.z, a.w, b.x, b.y, b.z, b.w};
#pragma unroll
  for (int j = 0; j < 8; ++j) {
    const u16 hh = f2bf(xv[j]);
    hv[j] = hh;
    lv[j] = f2bf(xv[j] - bf2f(hh));
  }
}

__device__ __forceinline__ void split8(const float* __restrict__ x,
                                       u16* __restrict__ h,
                                       u16* __restrict__ l, size_t i0)
{
  ushort8v hv, lv;
  split8v(x + i0, hv, lv);
  *(ushort8v*)(h + i0) = hv;
  *(ushort8v*)(l + i0) = lv;
}

__global__ __launch_bounds__(256) void cast_split_x_kernel(
    const float* __restrict__ x0, const float* __restrict__ x1,
    const float* __restrict__ x2, u16* __restrict__ base)
{
  const int z = blockIdx.z;
  const float* x = (z == 0) ? x0 : (z == 1) ? x1 : x2;
  u16* h = base + (size_t)z * (2 * (size_t)N1);
  u16* l = h + N1;
  const size_t i0 = ((size_t)blockIdx.x * 256 + threadIdx.x) * 8;
  split8(x, h, l, i0);
}

__global__ __launch_bounds__(256) void cast_split_w_kernel(
    const float* __restrict__ w0, const float* __restrict__ w1,
    const float* __restrict__ w2, const float* __restrict__ w3,
    u16* __restrict__ wbase, u16* __restrict__ wobase)
{
  const int z = blockIdx.z;
  const float* w = (z == 0) ? w0 : (z == 1) ? w1 : (z == 2) ? w2 : w3;
  u16* h = (z < 3) ? (wbase + (size_t)z * (2 * (size_t)N2)) : wobase;
  u16* l = h + N2;
  const size_t i0 = ((size_t)blockIdx.x * 256 + threadIdx.x) * 8;
  split8(w, h, l, i0);
}

__global__ __launch_bounds__(256) void cast_split_one_kernel(
    const float* __restrict__ x, u16* __restrict__ h, u16* __restrict__ l)
{
  const size_t i0 = ((size_t)blockIdx.x * 256 + threadIdx.x) * 8;
  split8(x, h, l, i0);
}

// ---------- async global->LDS (16B/lane, wave-uniform LDS base) ----------
__device__ __forceinline__ void async16(const void* g, void* l) {
  __builtin_amdgcn_global_load_lds(
      (const __attribute__((address_space(1))) void*)g,
      (__attribute__((address_space(3))) void*)l, 16, 0, 0);
}

// ===================== bf16x3 split MFMA GEMM (unchanged) =====================
__device__ __forceinline__ void gemm_mfma_body(
    const u16* __restrict__ XH, const u16* __restrict__ XL,
    const u16* __restrict__ WH, const u16* __restrict__ WL,
    const float* __restrict__ bias, float* __restrict__ out, const int headsplit)
{
  __shared__ __align__(16) u16 AsH[128][32];
  __shared__ __align__(16) u16 AsL[128][32];
  __shared__ __align__(16) u16 BsH[128][32];
  __shared__ __align__(16) u16 BsL[128][32];

  const int tid  = threadIdx.x;
  const int wid  = tid >> 6;
  const int lane = tid & 63;
  const int m0 = blockIdx.x * 128;
  const int n0 = blockIdx.y * 128;
  const int wr = (wid >> 1) * 64;
  const int wc = (wid & 1) * 64;

  const int c0   = wid * 2;
  const int srow = lane >> 2;
  const int scol = (lane & 3) * 8;

  const int fr = lane & 15;
  const int fg = (lane >> 4) * 8;

  float4v acc[4][4] = {};

  for (int k0 = 0; k0 < EMB; k0 += 32) {
#pragma unroll
    for (int cc = 0; cc < 2; ++cc) {
      const int c  = c0 + cc;
      const size_t ga = (size_t)(m0 + c * 16 + srow) * EMB + (k0 + scol);
      const size_t gb = (size_t)(n0 + c * 16 + srow) * EMB + (k0 + scol);
      async16(XH + ga, &AsH[c * 16][0]);
      async16(XL + ga, &AsL[c * 16][0]);
      async16(WH + gb, &BsH[c * 16][0]);
      async16(WL + gb, &BsL[c * 16][0]);
    }
    __syncthreads();

    short8v aH[4], aL[4], bH[4], bL[4];
#pragma unroll
    for (int i = 0; i < 4; ++i) {
      aH[i] = *(const short8v*)&AsH[wr + i * 16 + fr][fg];
      aL[i] = *(const short8v*)&AsL[wr + i * 16 + fr][fg];
      bH[i] = *(const short8v*)&BsH[wc + i * 16 + fr][fg];
      bL[i] = *(const short8v*)&BsL[wc + i * 16 + fr][fg];
    }
#pragma unroll
    for (int i = 0; i < 4; ++i)
#pragma unroll
      for (int j = 0; j < 4; ++j) {
        acc[i][j] = __builtin_amdgcn_mfma_f32_16x16x32_bf16(aH[i], bH[j], acc[i][j], 0, 0, 0);
        acc[i][j] = __builtin_amdgcn_mfma_f32_16x16x32_bf16(aH[i], bL[j], acc[i][j], 0, 0, 0);
        acc[i][j] = __builtin_amdgcn_mfma_f32_16x16x32_bf16(aL[i], bH[j], acc[i][j], 0, 0, 0);
      }
    __syncthreads();
  }

  const int rbase = (lane >> 4) * 4;
#pragma unroll
  for (int j = 0; j < 4; ++j) {
    const int col = n0 + wc + j * 16 + fr;
    const float bv = bias[col];
#pragma unroll
    for (int i = 0; i < 4; ++i) {
#pragma unroll
      for (int r = 0; r < 4; ++r) {
        const int m = m0 + wr + i * 16 + rbase + r;
        const float val = acc[i][j][r] + bv;
        if (headsplit) {
          const int s = m >> 1, b = m & 1;
          const int h = col >> 6, d = col & 63;
          out[((size_t)(b * NHEAD + h) * SEQ + s) * HD + d] = val;
        } else {
          out[(size_t)m * EMB + col] = val;
        }
      }
    }
  }
}

__global__ __launch_bounds__(256) void qkv_gemm_mfma_kernel(
    const u16* __restrict__ sc,
    const float* __restrict__ bq, const float* __restrict__ bk,
    const float* __restrict__ bv, float* __restrict__ outbase)
{
  const int z = blockIdx.z;
  const u16* XH = sc + (size_t)z * (2 * (size_t)N1);
  const u16* XL = XH + N1;
  const u16* WH = sc + 6 * (size_t)N1 + (size_t)z * (2 * (size_t)N2);
  const u16* WL = WH + N2;
  const float* bias = (z == 0) ? bq : (z == 1) ? bk : bv;
  gemm_mfma_body(XH, XL, WH, WL, bias, outbase + (size_t)z * N1, 1);
}

__global__ __launch_bounds__(256) void oproj_mfma_kernel(
    const u16* __restrict__ XH, const u16* __restrict__ XL,
    const u16* __restrict__ WH, const u16* __restrict__ WL,
    const float* __restrict__ bias, float* __restrict__ out)
{
  gemm_mfma_body(XH, XL, WH, WL, bias, out, 0);
}

// ===================== attn plane cast =====================
// K planes: per n, subtile grid (s>>4, d>>5), 16 rows x 32 d, element (s,d) at
//   ((s>>4)*2 + (d>>5))*512 + (((d>>3)&3)*16 + (s&15))*8 + (d&7)
// -> an MFMA B-frag read (row=s) is subtile_base + lane*8 u16 (conflict-free,
//    async16-linear).
// VT planes: per n, subtile grid (d>>4, s>>5), 16 d x 32 k, element (d,s) at
//   ((d>>4)*64 + (s>>5))*512 + (((s>>3)&3)*16 + (d&15))*8 + (s&7)
__global__ __launch_bounds__(256) void attn_cast_kernel(
    const float* __restrict__ kh, const float* __restrict__ vh,
    u16* __restrict__ KH, u16* __restrict__ KL,
    u16* __restrict__ VTH, u16* __restrict__ VTL)
{
  const size_t f = (size_t)blockIdx.x * 256 + threadIdx.x;
  if (blockIdx.z == 0) {
    const int o = (int)(f & 7);
    const int s = (int)((f >> 3) & 2047);
    const int n = (int)(f >> 14);
    ushort8v hv, lv;
    split8v(kh + ((size_t)n * SEQ + s) * HD + o * 8, hv, lv);
    const size_t idx = (size_t)n * PLANE
        + (size_t)(((s >> 4) * 2 + (o >> 2)) * 512)
        + (size_t)((((o & 3) * 16) + (s & 15)) * 8);
    *(ushort8v*)(KH + idx) = hv;
    *(ushort8v*)(KL + idx) = lv;
  } else {
    const int l = (int)(f & 63);
    const size_t sc_ = f >> 6;
    const int c = (int)(sc_ & 63);
    const int j = (int)((sc_ >> 6) & 3);
    const int n = (int)(sc_ >> 8);
    const int d  = j * 16 + (l & 15);
    const int kb = c * 32 + (l >> 4) * 8;
    ushort8v hv, lv;
#pragma unroll
    for (int e = 0; e < 8; ++e) {
      const float x = vh[((size_t)n * SEQ + kb + e) * HD + d];
      const u16 hh = f2bf(x);
      hv[e] = hh;
      lv[e] = f2bf(x - bf2f(hh));
    }
    const size_t idx = (size_t)n * PLANE + (size_t)((j * 64 + c) * 512) + (size_t)l * 8;
    *(ushort8v*)(VTH + idx) = hv;
    *(ushort8v*)(VTL + idx) = lv;
  }
}

// ===================== MFMA fused attention (two-sweep) =====================
// Block = 256 threads (4 waves), one (n, 64-query tile). Sweep 1: scores
// (bf16x3 MFMA) -> exp -> row-sums + PV (P bf16 x V hi/lo) -> normalized ctx.
// Sweep 2: recompute identical scores, write normalized weights to attnw.
// LDS map (u16 units): QH 0, QL 4096, KH 8192 (P aliases), KL 12288,
// VTH 16384, VTL 20480. Total 48K + small floats -> 3 blocks/CU.
__global__ __launch_bounds__(256) void attn_mfma_kernel(
    const float* __restrict__ Qf,
    const u16* __restrict__ KH, const u16* __restrict__ KL,
    const u16* __restrict__ VTH, const u16* __restrict__ VTL,
    float* __restrict__ attnw, float* __restrict__ ctxb)
{
  __shared__ __align__(16) u16 lds[24576];
  __shared__ float rsred[2][64];
  __shared__ float invs[64];

  const int tid = threadIdx.x;
  const int w   = tid >> 6;
  const int l   = tid & 63;
  const int n   = blockIdx.y;
  const int q0  = blockIdx.x * 64;

  const float* Qn  = Qf  + ((size_t)n * SEQ + q0) * HD;
  const u16* KHn  = KH  + (size_t)n * PLANE;
  const u16* KLn  = KL  + (size_t)n * PLANE;
  const u16* VTHn = VTH + (size_t)n * PLANE;
  const u16* VTLn = VTL + (size_t)n * PLANE;

  // ---- stage Q: split fp32 -> hi/lo subtile LDS (once) ----
#pragma unroll
  for (int rr = 0; rr < 2; ++rr) {
    const int slot = tid * 2 + rr;        // 0..511
    const int o = slot & 7, r = slot >> 3;
    ushort8v hv, lv;
    split8v(Qn + (size_t)r * HD + o * 8, hv, lv);
    const int idx = (((r >> 4) * 2 + (o >> 2)) * 512) + (((o & 3) * 16 + (r & 15)) * 8);
    *(ushort8v*)&lds[idx] = hv;
    *(ushort8v*)&lds[4096 + idx] = lv;
  }
  __syncthreads();

  const int wq = (w >> 1) * 32;   // wave q-rows (also ctx rows)
  const int wk = (w & 1) * 32;    // wave k-cols (sweep) / d-cols (PV)
  const int fr = l & 15;
  const int fg = l >> 4;

  // hoist Q-hi fragments (Q LDS persists through both sweeps)
  short8v aQh[2][2];
#pragma unroll
  for (int mi = 0; mi < 2; ++mi)
#pragma unroll
    for (int dc = 0; dc < 2; ++dc)
      aQh[mi][dc] = *(const short8v*)&lds[((((wq >> 4) + mi) * 2 + dc) * 512) + l * 8];

  float4v ctx[2][2] = {};
  float prow[2][4] = {};

  // ======== sweep 1: ctx + row sums ========
  for (int kt = 0; kt < SEQ / 64; ++kt) {
    const int k0 = kt * 64;
    __syncthreads();   // prior tile's LDS reads complete
    {
      const int base_g = (k0 >> 4) * 2;
#pragma unroll
      for (int cc = 0; cc < 2; ++cc) {
        const int s = w * 2 + cc;              // 0..7 subtile slot
        const int dst = s * 512;
        const size_t gk = (size_t)(base_g + s) * 512 + (size_t)l * 8;
        async16(KHn + gk, &lds[8192 + dst]);
        async16(KLn + gk, &lds[12288 + dst]);
        const size_t gv = (size_t)((s >> 1) * 64 + (k0 >> 5) + (s & 1)) * 512 + (size_t)l * 8;
        async16(VTHn + gv, &lds[16384 + dst]);
        async16(VTLn + gv, &lds[20480 + dst]);
      }
    }
    __syncthreads();   // staging complete (drains vmcnt)

    // ---- QK^T (x3) ----
    short8v aQl[2][2];
#pragma unroll
    for (int mi = 0; mi < 2; ++mi)
#pragma unroll
      for (int dc = 0; dc < 2; ++dc)
        aQl[mi][dc] = *(const short8v*)&lds[4096 + ((((wq >> 4) + mi) * 2 + dc) * 512) + l * 8];

    float4v sacc[2][2] = {};
#pragma unroll
    for (int ni = 0; ni < 2; ++ni) {
      short8v bKh[2], bKl[2];
#pragma unroll
      for (int dc = 0; dc < 2; ++dc) {
        const int kb = ((((wk >> 4) + ni) * 2 + dc) * 512) + l * 8;
        bKh[dc] = *(const short8v*)&lds[8192 + kb];
        bKl[dc] = *(const short8v*)&lds[12288 + kb];
      }
#pragma unroll
      for (int mi = 0; mi < 2; ++mi)
#pragma unroll
        for (int dc = 0; dc < 2; ++dc) {
          sacc[mi][ni] = __builtin_amdgcn_mfma_f32_16x16x32_bf16(aQh[mi][dc], bKh[dc], sacc[mi][ni], 0, 0, 0);
          sacc[mi][ni] = __builtin_amdgcn_mfma_f32_16x16x32_bf16(aQh[mi][dc], bKl[dc], sacc[mi][ni], 0, 0, 0);
          sacc[mi][ni] = __builtin_amdgcn_mfma_f32_16x16x32_bf16(aQl[mi][dc], bKh[dc], sacc[mi][ni], 0, 0, 0);
        }
    }
    __syncthreads();   // all K reads done; P may overwrite KH space

    // ---- exp, row-sum partials, P (bf16) -> LDS ----
#pragma unroll
    for (int mi = 0; mi < 2; ++mi) {
      const int qi = (wq >> 4) + mi;
#pragma unroll
      for (int ni = 0; ni < 2; ++ni) {
        const int kl_ = wk + ni * 16 + fr;
        const int pbase = 8192 + (qi * 2 + (kl_ >> 5)) * 512 + (kl_ & 7);
        const int koff = ((kl_ >> 3) & 3) * 16;
#pragma unroll
        for (int r = 0; r < 4; ++r) {
          const float e = __expf(sacc[mi][ni][r] * 0.125f);
          prow[mi][r] += e;
          lds[pbase + (koff + fg * 4 + r) * 8] = f2bf(e);
        }
      }
    }
    __syncthreads();   // P ready

    // ---- PV: ctx quadrant rows wq, cols wk ----
    short8v aP[2][2], bVh[2][2], bVl[2][2];
#pragma unroll
    for (int mi = 0; mi < 2; ++mi)
#pragma unroll
      for (int kc = 0; kc < 2; ++kc)
        aP[mi][kc] = *(const short8v*)&lds[8192 + ((((wq >> 4) + mi) * 2 + kc) * 512) + l * 8];
#pragma unroll
    for (int ji = 0; ji < 2; ++ji)
#pragma unroll
      for (int kc = 0; kc < 2; ++kc) {
        const int vb = ((((wk >> 4) + ji) * 2 + kc) * 512) + l * 8;
        bVh[ji][kc] = *(const short8v*)&lds[16384 + vb];
        bVl[ji][kc] = *(const short8v*)&lds[20480 + vb];
      }
#pragma unroll
    for (int mi = 0; mi < 2; ++mi)
#pragma unroll
      for (int ji = 0; ji < 2; ++ji)
#pragma unroll
        for (int kc = 0; kc < 2; ++kc) {
          ctx[mi][ji] = __builtin_amdgcn_mfma_f32_16x16x32_bf16(aP[mi][kc], bVh[ji][kc], ctx[mi][ji], 0, 0, 0);
          ctx[mi][ji] = __builtin_amdgcn_mfma_f32_16x16x32_bf16(aP[mi][kc], bVl[ji][kc], ctx[mi][ji], 0, 0, 0);
        }
  }

  // ---- row-sum reduce across 16 col-lanes, then 2 k-halves ----
#pragma unroll
  for (int mi = 0; mi < 2; ++mi)
#pragma unroll
    for (int r = 0; r < 4; ++r) {
      float v = prow[mi][r];
      v += __shfl_xor(v, 1, 64); v += __shfl_xor(v, 2, 64);
      v += __shfl_xor(v, 4, 64); v += __shfl_xor(v, 8, 64);
      prow[mi][r] = v;
    }
  if (fr == 0) {
#pragma unroll
    for (int mi = 0; mi < 2; ++mi)
#pragma unroll
      for (int r = 0; r < 4; ++r)
        rsred[w & 1][wq + mi * 16 + fg * 4 + r] = prow[mi][r];
  }
  __syncthreads();
  if (tid < 64) invs[tid] = 1.0f / (rsred[0][tid] + rsred[1][tid]);
  __syncthreads();

  float myinv[2][4];
#pragma unroll
  for (int mi = 0; mi < 2; ++mi)
#pragma unroll
    for (int r = 0; r < 4; ++r)
      myinv[mi][r] = invs[wq + mi * 16 + fg * 4 + r];

  // ---- normalized ctx -> token-major ctxb ----
  {
    const int bb = n / NHEAD, hh = n % NHEAD;
#pragma unroll
    for (int mi = 0; mi < 2; ++mi)
#pragma unroll
      for (int ji = 0; ji < 2; ++ji)
#pragma unroll
        for (int r = 0; r < 4; ++r) {
          const int ql_ = wq + mi * 16 + fg * 4 + r;
          const int d   = wk + ji * 16 + fr;
          const int rgl = (q0 + ql_) * BATCH + bb;
          ctxb[(size_t)rgl * EMB + hh * HD + d] = ctx[mi][ji][r] * myinv[mi][r];
        }
  }

  // ======== sweep 2: recompute scores, write normalized weights ========
  float* awn = attnw + ((size_t)n * SEQ + q0) * SEQ;
  for (int kt = 0; kt < SEQ / 64; ++kt) {
    const int k0 = kt * 64;
    __syncthreads();
    {
      const int base_g = (k0 >> 4) * 2;
#pragma unroll
      for (int cc = 0; cc < 4; ++cc) {
        const int s = w * 4 + cc;            // 0..15: plane p=s>>3, sub=s&7
        const int sub = s & 7;
        const size_t gk = (size_t)(base_g + sub) * 512 + (size_t)l * 8;
        if (s < 8) async16(KHn + gk, &lds[8192 + sub * 512]);
        else       async16(KLn + gk, &lds[12288 + sub * 512]);
      }
    }
    __syncthreads();

    short8v aQl[2][2];
#pragma unroll
    for (int mi = 0; mi < 2; ++mi)
#pragma unroll
      for (int dc = 0; dc < 2; ++dc)
        aQl[mi][dc] = *(const short8v*)&lds[4096 + ((((wq >> 4) + mi) * 2 + dc) * 512) + l * 8];

    float4v sacc[2][2] = {};
#pragma unroll
    for (int ni = 0; ni < 2; ++ni) {
      short8v bKh[2], bKl[2];
#pragma unroll
      for (int dc = 0; dc < 2; ++dc) {
        const int kb = ((((wk >> 4) + ni) * 2 + dc) * 512) + l * 8;
        bKh[dc] = *(const short8v*)&lds[8192 + kb];
        bKl[dc] = *(const short8v*)&lds[12288 + kb];
      }
#pragma unroll
      for (int mi = 0; mi < 2; ++mi)
#pragma unroll
        for (int dc = 0; dc < 2; ++dc) {
          sacc[mi][ni] = __builtin_amdgcn_mfma_f32_16x16x32_bf16(aQh[mi][dc], bKh[dc], sacc[mi][ni], 0, 0, 0);
          sacc[mi][ni] = __builtin_amdgcn_mfma_f32_16x16x32_bf16(aQh[mi][dc], bKl[dc], sacc[mi][ni], 0, 0, 0);
          sacc[mi][ni] = __builtin_amdgcn_mfma_f32_16x16x32_bf16(aQl[mi][dc], bKh[dc], sacc[mi][ni], 0, 0, 0);
        }
    }

#pragma unroll
    for (int mi = 0; mi < 2; ++mi)
#pragma unroll
      for (int ni = 0; ni < 2; ++ni)
#pragma unroll
        for (int r = 0; r < 4; ++r) {
          const int ql_ = wq + mi * 16 + fg * 4 + r;
          const int kl_ = wk + ni * 16 + fr;
          awn[(size_t)ql_ * SEQ + k0 + kl_] =
              __expf(sacc[mi][ni][r] * 0.125f) * myinv[mi][r];
        }
  }
}

// ===================== launch =====================
extern "C" void kernel_launch(void* const* d_in, const int* in_sizes, int n_in,
                              void* d_out, int out_size, void* d_ws, size_t ws_size,
                              hipStream_t stream)
{
  (void)in_sizes; (void)n_in; (void)out_size; (void)ws_size;

  const float* q  = (const float*)d_in[0];
  const float* k  = (const float*)d_in[1];
  const float* v  = (const float*)d_in[2];
  const float* wq = (const float*)d_in[3];
  const float* wk = (const float*)d_in[4];
  const float* wv = (const float*)d_in[5];
  const float* bq = (const float*)d_in[6];
  const float* bk = (const float*)d_in[7];
  const float* bv = (const float*)d_in[8];
  const float* wo = (const float*)d_in[9];
  const float* bo = (const float*)d_in[10];

  float* out = (float*)d_out;
  float* attnw = out + (size_t)N1;               // output first, then weights

  float* ws   = (float*)d_ws;
  float* qh   = ws;                               // [24][2048][64] fp32
  float* kh   = ws + (size_t)N1;
  float* vh   = ws + 2 * (size_t)N1;
  float* ctxb = ws + 3 * (size_t)N1;              // [4096][768] fp32

  // scratch: X/W input planes in attnw region (overwritten by attn sweep 2
  // afterwards -> safe); W_O planes + K/VT planes in ws.
  u16* sc  = (u16*)attnw;                         // 6*N1 + 6*N2 u16
  u16* wpl = sc + 6 * (size_t)N1;
  u16* wopl = (u16*)(ws + 4 * (size_t)N1 + 65536);
  // K/VT bf16 subtile planes: ws[5*N1, 7*N1) floats (assumes ws >= 7*N1*4 B = 88 MB;
  // prior rounds used ~53 MB of the same workspace)
  u16* KHp  = (u16*)(ws + 5 * (size_t)N1);
  u16* KLp  = KHp + N1;
  u16* VTHp = KLp + N1;
  u16* VTLp = VTHp + N1;
  // ctx planes reuse qh region (dead after attn)
  u16* ctxH = (u16*)qh;
  u16* ctxL = ctxH + N1;

  cast_split_x_kernel<<<dim3(N1 / 2048, 1, 3), 256, 0, stream>>>(q, k, v, sc);
  cast_split_w_kernel<<<dim3(N2 / 2048, 1, 4), 256, 0, stream>>>(wq, wk, wv, wo, wpl, wopl);

  qkv_gemm_mfma_kernel<<<dim3(MROWS / 128, EMB / 128, 3), 256, 0, stream>>>(
      sc, bq, bk, bv, qh);

  attn_cast_kernel<<<dim3(1536, 1, 2), 256, 0, stream>>>(
      kh, vh, KHp, KLp, VTHp, VTLp);

  attn_mfma_kernel<<<dim3(SEQ / 64, NHT), 256, 0, stream>>>(
      qh, KHp, KLp, VTHp, VTLp, attnw, ctxb);

  cast_split_one_kernel<<<dim3(N1 / 2048), 256, 0, stream>>>(ctxb, ctxH, ctxL);

  oproj_mfma_kernel<<<dim3(MROWS / 128, EMB / 128), 256, 0, stream>>>(
      ctxH, ctxL, wopl, wopl + N2, bo, out);
}